// Round 2
// baseline (284.738 us; speedup 1.0000x reference)
//
#include <hip/hip_runtime.h>
#include <hip/hip_bf16.h>

// DCNv2 fused: prep (bf16 pair-texture + weight relayout) + fused im2col+GEMM.
// B=8 C=256 H=W=64 O=256 3x3 s1 p1 d1 DG=1.
// GEMM view: per b, out[256,4096] = W'[256,2304] @ colsT^T ; K-order = k*256+c.

typedef unsigned int u32;
typedef unsigned short u16;
typedef __bf16 bf16x8 __attribute__((ext_vector_type(8)));
typedef float f32x4 __attribute__((ext_vector_type(4)));

#define NSP   4096
#define TOT   8388608      // 8*256*4096 input elements
#define KTOT  2304         // C*9
#define NSTEP 36           // 2304/64

__device__ __forceinline__ u32 f2bf(float f) {  // RNE f32->bf16 (finite data)
  u32 u = __float_as_uint(f);
  return (u + 0x7fffu + ((u >> 16) & 1u)) >> 16;
}
__device__ __forceinline__ u32 pk2(float a, float b) { return f2bf(a) | (f2bf(b) << 16); }
__device__ __forceinline__ float lo16(u32 u) { return __uint_as_float(u << 16); }
__device__ __forceinline__ float hi16(u32 u) { return __uint_as_float(u & 0xffff0000u); }

// D[i] = (bf16(in[i]) , bf16(in[i+1])) -- one aligned dword = one bilinear row-pair.
__global__ void prep_input(const float* __restrict__ in, u32* __restrict__ D) {
  int t = blockIdx.x * 256 + threadIdx.x;
  int i0 = t << 2;
  float4 v = *(const float4*)(in + i0);
  float e = (i0 + 4 < TOT) ? in[i0 + 4] : 0.0f;
  uint4 d;
  d.x = pk2(v.x, v.y);
  d.y = pk2(v.y, v.z);
  d.z = pk2(v.z, v.w);
  d.w = pk2(v.w, e);
  *(uint4*)(D + i0) = d;
}

// W'[o][k*256+c] = bf16(weight[o][c][k]) , k = ki*3+kj
__global__ void prep_weight(const float* __restrict__ w, u16* __restrict__ Wp) {
  int idx = blockIdx.x * 256 + threadIdx.x;   // < 256*2304
  int o = idx / KTOT;
  int r = idx - o * KTOT;
  int k = r >> 8, c = r & 255;
  Wp[idx] = (u16)f2bf(w[o * KTOT + c * 9 + k]);
}

__global__ __launch_bounds__(512, 2) void dcn_main(
    const u32* __restrict__ D, const u16* __restrict__ Wp,
    const float* __restrict__ off, const float* __restrict__ msk,
    const float* __restrict__ bias, float* __restrict__ out)
{
  __shared__ u16 wb[2][256 * 64];   // weight tile, XOR-swizzled rows   (64 KiB)
  __shared__ u16 ct[2][128 * 64];   // colsT tile [n][kappa], swizzled  (32 KiB)
  __shared__ int   pOf[2][9 * 128]; // row offsets A/B per (k, n-local) ( 9 KiB)
  __shared__ float pW[4][9 * 128];  // 4 corner weights (mask folded)   (18 KiB)

  const int tid = threadIdx.x;
  const int bid = blockIdx.x;
  const int b  = bid >> 5;
  const int n0 = (bid & 31) << 7;

  // ---------- per-(k, n) bilinear params ----------
  for (int idx = tid; idx < 9 * 128; idx += 512) {
    int k = idx >> 7, nl = idx & 127;
    int n = n0 + nl;
    int h = n >> 6, w = n & 63;
    int ki = k / 3, kj = k - ki * 3;
    float offy = off[(b * 18 + 2 * k) * NSP + n];
    float offx = off[(b * 18 + 2 * k + 1) * NSP + n];
    float mval = msk[(b * 9 + k) * NSP + n];
    float py = (float)(h - 1 + ki) + offy;
    float px = (float)(w - 1 + kj) + offx;
    float y0f = floorf(py), x0f = floorf(px);
    float ly = py - y0f, lx = px - x0f;
    int y0 = (int)y0f, x0 = (int)x0f;
    int xl = min(max(x0, 0), 62);          // pair (xl, xl+1) stays inside the row
    float ws0 = 0.f, ws1 = 0.f;            // slot weights within the pair
    if (x0 >= 0 && x0 <= 63)         { if (x0 == xl)     ws0 += 1.f - lx; else ws1 += 1.f - lx; }
    if (x0 + 1 >= 0 && x0 + 1 <= 63) { if (x0 + 1 == xl) ws0 += lx;       else ws1 += lx; }
    float wy0 = 1.f - ly, wy1 = ly;
    int oA = 0, oB = 0;
    if (y0 >= 0 && y0 < 64) oA = (y0 << 6) + xl; else wy0 = 0.f;
    if (y0 + 1 >= 0 && y0 + 1 < 64) oB = ((y0 + 1) << 6) + xl; else wy1 = 0.f;
    pOf[0][idx] = oA; pOf[1][idx] = oB;
    pW[0][idx] = wy0 * ws0 * mval;
    pW[1][idx] = wy0 * ws1 * mval;
    pW[2][idx] = wy1 * ws0 * mval;
    pW[3][idx] = wy1 * ws1 * mval;
  }
  __syncthreads();

  const int nl  = tid & 127;
  const int og  = tid >> 7;          // 0..3  (octet group for sampling)
  const int wv  = tid >> 6, lane = tid & 63;
  const int wm  = wv & 3,  wn   = wv >> 2;
  const int lr  = lane & 15, lg = lane >> 4;

  u32  gu[2][2][8];                  // gathers [rowA/rowB][grp][channel j]
  uint4 wq[4];                       // weight staging regs
  float sw[4]; int soA, soB;

  f32x4 acc[4][4] = {};

  auto issue = [&](int kk) {         // issue all global loads for step kk
    int k = kk >> 2, c0 = (kk & 3) << 6;
    int pi = (k << 7) + nl;
    soA = pOf[0][pi]; soB = pOf[1][pi];
    sw[0] = pW[0][pi]; sw[1] = pW[1][pi]; sw[2] = pW[2][pi]; sw[3] = pW[3][pi];
    u32 cbase = ((u32)((b << 8) + c0 + (og << 3))) << 12;
#pragma unroll
    for (int g = 0; g < 2; ++g) {
      u32 gb = cbase + (g ? (32u << 12) : 0u);
#pragma unroll
      for (int j = 0; j < 8; ++j) {
        gu[0][g][j] = D[gb + (j << 12) + (u32)soA];
        gu[1][g][j] = D[gb + (j << 12) + (u32)soB];
      }
    }
    int kap0 = kk << 6;
#pragma unroll
    for (int i = 0; i < 4; ++i) {
      int q = tid + (i << 9);
      int o = q >> 3, s = q & 7;
      wq[i] = *(const uint4*)(Wp + o * KTOT + kap0 + (s << 3));
    }
  };

  auto commit = [&](u16* ctb, u16* wbb) {   // combine + LDS writes (swizzled)
#pragma unroll
    for (int g = 0; g < 2; ++g) {
      u32 o4[4];
#pragma unroll
      for (int jj = 0; jj < 4; ++jj) {
        u32 a0 = gu[0][g][2 * jj],     b0 = gu[1][g][2 * jj];
        u32 a1 = gu[0][g][2 * jj + 1], b1 = gu[1][g][2 * jj + 1];
        float v0 = sw[0] * lo16(a0) + sw[1] * hi16(a0) + sw[2] * lo16(b0) + sw[3] * hi16(b0);
        float v1 = sw[0] * lo16(a1) + sw[1] * hi16(a1) + sw[2] * lo16(b1) + sw[3] * hi16(b1);
        o4[jj] = pk2(v0, v1);
      }
      int oct = og + (g << 2);
      int byteoff = nl * 128 + ((oct ^ (nl & 7)) << 4);
      *(uint4*)((char*)ctb + byteoff) = make_uint4(o4[0], o4[1], o4[2], o4[3]);
    }
#pragma unroll
    for (int i = 0; i < 4; ++i) {
      int q = tid + (i << 9);
      int o = q >> 3, s = q & 7;
      int byteoff = o * 128 + ((s ^ (o & 7)) << 4);
      *(uint4*)((char*)wbb + byteoff) = wq[i];
    }
  };

  auto domfma = [&](const u16* ctb, const u16* wbb) {
#pragma unroll
    for (int kh = 0; kh < 2; ++kh) {
      int c16 = (kh << 2) + lg;
      bf16x8 bfr[4];
#pragma unroll
      for (int fn = 0; fn < 4; ++fn) {
        int nrow = (wn << 6) + (fn << 4) + lr;
        bfr[fn] = *(const bf16x8*)((const char*)ctb + nrow * 128 + ((c16 ^ (nrow & 7)) << 4));
      }
#pragma unroll
      for (int fm = 0; fm < 4; ++fm) {
        int orow = (wm << 6) + (fm << 4) + lr;
        bf16x8 af = *(const bf16x8*)((const char*)wbb + orow * 128 + ((c16 ^ (orow & 7)) << 4));
#pragma unroll
        for (int fn = 0; fn < 4; ++fn)
          acc[fm][fn] = __builtin_amdgcn_mfma_f32_16x16x32_bf16(af, bfr[fn], acc[fm][fn], 0, 0, 0);
      }
    }
  };

  // ---------- main K loop (double-buffered) ----------
  issue(0);
  commit(ct[0], wb[0]);
  __syncthreads();
  int cur = 0;
  for (int kk = 0; kk < NSTEP; ++kk) {
    int nx = cur ^ 1;
    if (kk + 1 < NSTEP) issue(kk + 1);     // gathers in flight during MFMA
    domfma(ct[cur], wb[cur]);
    if (kk + 1 < NSTEP) commit(ct[nx], wb[nx]);
    __syncthreads();
    cur = nx;
  }

  // ---------- epilogue ----------
#pragma unroll
  for (int fm = 0; fm < 4; ++fm) {
    int mb = (wm << 6) + (fm << 4) + (lg << 2);
#pragma unroll
    for (int r = 0; r < 4; ++r) {
      int m = mb + r;
      float bv = bias[m];
      int obase = (((b << 8) + m) << 12) + n0 + (wn << 6) + lr;
#pragma unroll
      for (int fn = 0; fn < 4; ++fn)
        out[obase + (fn << 4)] = acc[fm][fn][r] + bv;
    }
  }
}

extern "C" void kernel_launch(void* const* d_in, const int* in_sizes, int n_in,
                              void* d_out, int out_size, void* d_ws, size_t ws_size,
                              hipStream_t stream) {
  const float* inp  = (const float*)d_in[0];
  const float* off  = (const float*)d_in[1];
  const float* msk  = (const float*)d_in[2];
  const float* wgt  = (const float*)d_in[3];
  const float* bias = (const float*)d_in[4];
  float* out = (float*)d_out;

  u32* D  = (u32*)d_ws;                                   // 33,554,432 B
  u16* Wp = (u16*)((char*)d_ws + (size_t)TOT * 4);        //  1,179,648 B (ws >= 34.8 MB)

  prep_input<<<TOT / 1024, 256, 0, stream>>>(inp, D);
  prep_weight<<<(256 * KTOT) / 256, 256, 0, stream>>>(wgt, Wp);
  dcn_main<<<256, 512, 0, stream>>>(D, Wp, off, msk, bias, out);
}

// Round 3
// 183.517 us; speedup vs baseline: 1.5516x; 1.5516x over previous
//
#include <hip/hip_runtime.h>
#include <hip/hip_bf16.h>

// DCNv2 fused, v2: NHWC bf16 texture + tap-inner K-order.
// B=8 C=256 H=W=64 O=256 3x3 s1 p1 d1 DG=1.
// kappa = cblk*576 + k*64 + ci  (cblk: 4 blocks of 64 ch, k: tap 0..8)
// per b: out[256,4096] = W'[256,2304] @ colsT^T

typedef unsigned int u32;
typedef unsigned short u16;
typedef __bf16 bf16x8 __attribute__((ext_vector_type(8)));
typedef float f32x4 __attribute__((ext_vector_type(4)));

#define NSP   4096
#define KTOT  2304
#define NSTEP 36

__device__ __forceinline__ u32 f2bf(float f) {  // RNE f32->bf16 (finite data)
  u32 u = __float_as_uint(f);
  return (u + 0x7fffu + ((u >> 16) & 1u)) >> 16;
}
__device__ __forceinline__ u32 pk2(float a, float b) { return f2bf(a) | (f2bf(b) << 16); }
__device__ __forceinline__ float lo16(u32 u) { return __uint_as_float(u << 16); }
__device__ __forceinline__ float hi16(u32 u) { return __uint_as_float(u & 0xffff0000u); }

// NCHW f32 -> NHWC bf16 transpose: Dc[b][y][x][c] = bf16(in[b][c][y][x])
// block = (b,y), 256 threads, LDS u32 [64][129] (x, c-pair), 2-way-free writes.
__global__ void prep_input(const float* __restrict__ in, u16* __restrict__ Dc) {
  __shared__ u32 T[64][129];
  int b = blockIdx.x >> 6, y = blockIdx.x & 63;
  const float* src = in + (size_t)b * 1048576 + y * 64;
  int x = threadIdx.x & 63, co = threadIdx.x >> 6;
#pragma unroll 4
  for (int r = 0; r < 32; ++r) {
    int cp = r * 4 + co;
    float v0 = src[(2 * cp) * NSP + x];
    float v1 = src[(2 * cp + 1) * NSP + x];
    T[x][cp] = pk2(v0, v1);
  }
  __syncthreads();
  u16* dst = Dc + (size_t)(b * 64 + y) * 16384;
#pragma unroll
  for (int p = 0; p < 8; ++p) {
    int t = p * 256 + threadIdx.x;          // 16B quad index; byte = t*16
    int xx = t >> 5, cp0 = (t & 31) << 2;
    uint4 v;
    v.x = T[xx][cp0]; v.y = T[xx][cp0 + 1]; v.z = T[xx][cp0 + 2]; v.w = T[xx][cp0 + 3];
    *(uint4*)((char*)dst + (size_t)t * 16) = v;
  }
}

// W'[o][cblk*576 + k*64 + ci] = bf16(weight[o][cblk*64+ci][k])
__global__ void prep_weight(const float* __restrict__ w, u16* __restrict__ Wp) {
  int idx = blockIdx.x * 256 + threadIdx.x;   // < 256*2304
  int o = idx / KTOT;
  int r = idx - o * KTOT;
  int cblk = r / 576, t2 = r - cblk * 576;
  int k = t2 >> 6, ci = t2 & 63;
  Wp[idx] = (u16)f2bf(w[o * KTOT + (cblk * 64 + ci) * 9 + k]);
}

__global__ __launch_bounds__(512, 2) void dcn_main(
    const u16* __restrict__ Dc, const u16* __restrict__ Wp,
    const float* __restrict__ off, const float* __restrict__ msk,
    const float* __restrict__ bias, float* __restrict__ out)
{
  __shared__ u16 wb[2][256 * 64];   // weight tile, XOR-swizzled   (64 KiB)
  __shared__ u16 ct[2][128 * 64];   // colsT tile [n][64], swizzled(32 KiB)
  __shared__ int   pOf[2][9 * 128]; // corner row-base offsets A/B ( 9 KiB)
  __shared__ float pW[4][9 * 128];  // 4 corner weights (mask folded)

  const int tid = threadIdx.x;
  const int bid = blockIdx.x;
  const int b  = bid >> 5;
  const int n0 = (bid & 31) << 7;

  // ---------- per-(k, n) bilinear params (unchanged, verified) ----------
  for (int idx = tid; idx < 9 * 128; idx += 512) {
    int k = idx >> 7, nl = idx & 127;
    int n = n0 + nl;
    int h = n >> 6, w = n & 63;
    int ki = k / 3, kj = k - ki * 3;
    float offy = off[(b * 18 + 2 * k) * NSP + n];
    float offx = off[(b * 18 + 2 * k + 1) * NSP + n];
    float mval = msk[(b * 9 + k) * NSP + n];
    float py = (float)(h - 1 + ki) + offy;
    float px = (float)(w - 1 + kj) + offx;
    float y0f = floorf(py), x0f = floorf(px);
    float ly = py - y0f, lx = px - x0f;
    int y0 = (int)y0f, x0 = (int)x0f;
    int xl = min(max(x0, 0), 62);           // pair (xl, xl+1) stays in row
    float ws0 = 0.f, ws1 = 0.f;
    if (x0 >= 0 && x0 <= 63)         { if (x0 == xl)     ws0 += 1.f - lx; else ws1 += 1.f - lx; }
    if (x0 + 1 >= 0 && x0 + 1 <= 63) { if (x0 + 1 == xl) ws0 += lx;       else ws1 += lx; }
    float wy0 = 1.f - ly, wy1 = ly;
    int oA = 0, oB = 0;
    if (y0 >= 0 && y0 < 64) oA = (y0 << 6) + xl; else wy0 = 0.f;
    if (y0 + 1 >= 0 && y0 + 1 < 64) oB = ((y0 + 1) << 6) + xl; else wy1 = 0.f;
    pOf[0][idx] = oA; pOf[1][idx] = oB;
    pW[0][idx] = wy0 * ws0 * mval;
    pW[1][idx] = wy0 * ws1 * mval;
    pW[2][idx] = wy1 * ws0 * mval;
    pW[3][idx] = wy1 * ws1 * mval;
  }
  __syncthreads();

  const char* Db = (const char*)Dc + (size_t)b * 2097152;  // NHWC plane of batch b
  const int wv  = tid >> 6, lane = tid & 63;
  const int wm  = wv & 3,  wn   = wv >> 2;
  const int lr  = lane & 15, lg = lane >> 4;

  uint4 gA0[2], gA1[2], gB0[2], gB1[2];   // corner gathers, 2 tuples/thread
  float sw2[2][4];
  uint4 wq[4];

  f32x4 acc[4][4] = {};

  auto issue = [&](int s) {               // all global loads for step s
    int cblk = s / 9;
    int k = s - cblk * 9;                 // tap-inner: 9 consecutive steps reuse lines
    u32 cb2 = (u32)(cblk << 7);
#pragma unroll
    for (int u = 0; u < 2; ++u) {
      int tup = tid + (u << 9);
      int nl2 = tup >> 3, c8 = tup & 7;
      int pi = (k << 7) + nl2;
      u32 ba = (u32)pOf[0][pi] * 512u + cb2 + (u32)(c8 << 4);
      u32 bb = (u32)pOf[1][pi] * 512u + cb2 + (u32)(c8 << 4);
      sw2[u][0] = pW[0][pi]; sw2[u][1] = pW[1][pi];
      sw2[u][2] = pW[2][pi]; sw2[u][3] = pW[3][pi];
      gA0[u] = *(const uint4*)(Db + ba);          // corner (y0, xl): 8 ch, 16B
      gA1[u] = *(const uint4*)(Db + ba + 512);    // (y0, xl+1)
      gB0[u] = *(const uint4*)(Db + bb);          // (y1, xl)
      gB1[u] = *(const uint4*)(Db + bb + 512);    // (y1, xl+1)
    }
    int kap0 = s << 6;
#pragma unroll
    for (int i = 0; i < 4; ++i) {
      int q = tid + (i << 9);
      int o = q >> 3, sft = q & 7;
      wq[i] = *(const uint4*)(Wp + o * KTOT + kap0 + (sft << 3));
    }
  };

  auto commit = [&](u16* ctb, u16* wbb) {  // blend + swizzled LDS writes
#pragma unroll
    for (int u = 0; u < 2; ++u) {
      int tup = tid + (u << 9);
      int nl2 = tup >> 3, c8 = tup & 7;
      u32 o4[4];
      const u32* a0p = (const u32*)&gA0[u];
      const u32* a1p = (const u32*)&gA1[u];
      const u32* b0p = (const u32*)&gB0[u];
      const u32* b1p = (const u32*)&gB1[u];
#pragma unroll
      for (int j = 0; j < 4; ++j) {
        u32 a0 = a0p[j], a1 = a1p[j], b0 = b0p[j], b1 = b1p[j];
        float vlo = sw2[u][0] * lo16(a0) + sw2[u][1] * lo16(a1)
                  + sw2[u][2] * lo16(b0) + sw2[u][3] * lo16(b1);
        float vhi = sw2[u][0] * hi16(a0) + sw2[u][1] * hi16(a1)
                  + sw2[u][2] * hi16(b0) + sw2[u][3] * hi16(b1);
        o4[j] = pk2(vlo, vhi);
      }
      int byteoff = nl2 * 128 + ((c8 ^ (nl2 & 7)) << 4);
      *(uint4*)((char*)ctb + byteoff) = make_uint4(o4[0], o4[1], o4[2], o4[3]);
    }
#pragma unroll
    for (int i = 0; i < 4; ++i) {
      int q = tid + (i << 9);
      int o = q >> 3, sft = q & 7;
      int byteoff = o * 128 + ((sft ^ (o & 7)) << 4);
      *(uint4*)((char*)wbb + byteoff) = wq[i];
    }
  };

  auto domfma = [&](const u16* ctb, const u16* wbb) {
#pragma unroll
    for (int kh = 0; kh < 2; ++kh) {
      int c16 = (kh << 2) + lg;
      bf16x8 bfr[4];
#pragma unroll
      for (int fn = 0; fn < 4; ++fn) {
        int nrow = (wn << 6) + (fn << 4) + lr;
        bfr[fn] = *(const bf16x8*)((const char*)ctb + nrow * 128 + ((c16 ^ (nrow & 7)) << 4));
      }
#pragma unroll
      for (int fm = 0; fm < 4; ++fm) {
        int orow = (wm << 6) + (fm << 4) + lr;
        bf16x8 af = *(const bf16x8*)((const char*)wbb + orow * 128 + ((c16 ^ (orow & 7)) << 4));
#pragma unroll
        for (int fn = 0; fn < 4; ++fn)
          acc[fm][fn] = __builtin_amdgcn_mfma_f32_16x16x32_bf16(af, bfr[fn], acc[fm][fn], 0, 0, 0);
      }
    }
  };

  // ---------- main K loop (double-buffered) ----------
  issue(0);
  commit(ct[0], wb[0]);
  __syncthreads();
  int cur = 0;
  for (int s = 0; s < NSTEP; ++s) {
    int nx = cur ^ 1;
    if (s + 1 < NSTEP) issue(s + 1);       // gathers in flight during MFMA
    domfma(ct[cur], wb[cur]);
    if (s + 1 < NSTEP) commit(ct[nx], wb[nx]);
    __syncthreads();
    cur = nx;
  }

  // ---------- epilogue ----------
#pragma unroll
  for (int fm = 0; fm < 4; ++fm) {
    int mb = (wm << 6) + (fm << 4) + (lg << 2);
#pragma unroll
    for (int r = 0; r < 4; ++r) {
      int m = mb + r;
      float bv = bias[m];
      int obase = (((b << 8) + m) << 12) + n0 + (wn << 6) + lr;
#pragma unroll
      for (int fn = 0; fn < 4; ++fn)
        out[obase + (fn << 4)] = acc[fm][fn][r] + bv;
    }
  }
}

extern "C" void kernel_launch(void* const* d_in, const int* in_sizes, int n_in,
                              void* d_out, int out_size, void* d_ws, size_t ws_size,
                              hipStream_t stream) {
  const float* inp  = (const float*)d_in[0];
  const float* off  = (const float*)d_in[1];
  const float* msk  = (const float*)d_in[2];
  const float* wgt  = (const float*)d_in[3];
  const float* bias = (const float*)d_in[4];
  float* out = (float*)d_out;

  u16* Dc = (u16*)d_ws;                                    // 16,777,216 B
  u16* Wp = (u16*)((char*)d_ws + (size_t)16777216);        //  1,179,648 B

  prep_input<<<512, 256, 0, stream>>>(inp, Dc);
  prep_weight<<<(256 * KTOT) / 256, 256, 0, stream>>>(wgt, Wp);
  dcn_main<<<256, 512, 0, stream>>>(Dc, Wp, off, msk, bias, out);
}